// Round 1
// baseline (375.667 us; speedup 1.0000x reference)
//
#include <hip/hip_runtime.h>
#include <cstdint>
#include <cstddef>

// ---------------------------------------------------------------------------
// DiT block: LN -> self-attn -> +res -> LN -> cross-attn -> +res -> LN -> MLP
// B=4 N=2048 M=512 E=512 CD=256 H=8 DH=64 MH=1024
// All GEMMs bf16 MFMA (16x16x32), fp32 accum. Residuals fp32.
// ---------------------------------------------------------------------------

typedef short short8 __attribute__((ext_vector_type(8)));
typedef float f32x4 __attribute__((ext_vector_type(4)));

__device__ __forceinline__ short f2bf(float f) {
  union { float f; unsigned u; } x; x.f = f;
  unsigned r = x.u + 0x7fffu + ((x.u >> 16) & 1u);  // RNE
  return (short)(r >> 16);
}

// ---------------- cast fp32 -> bf16 (8 elems/thread) ----------------
__global__ __launch_bounds__(256) void cast_bf16_kernel(
    const float* __restrict__ src, short* __restrict__ dst, int n) {
  int idx = (blockIdx.x * 256 + threadIdx.x) * 8;
  if (idx >= n) return;
  float4 f0 = *(const float4*)(src + idx);
  float4 f1 = *(const float4*)(src + idx + 4);
  short8 o;
  o[0] = f2bf(f0.x); o[1] = f2bf(f0.y); o[2] = f2bf(f0.z); o[3] = f2bf(f0.w);
  o[4] = f2bf(f1.x); o[5] = f2bf(f1.y); o[6] = f2bf(f1.z); o[7] = f2bf(f1.w);
  *(short8*)(dst + idx) = o;
}

// ---------------- LayerNorm over 512 cols, 1 wave/row, bf16 out ----------------
__global__ __launch_bounds__(256) void ln_kernel(
    const float* __restrict__ x, short* __restrict__ out, int nrows) {
  int row = blockIdx.x * 4 + (threadIdx.x >> 6);
  int lane = threadIdx.x & 63;
  if (row >= nrows) return;
  const float* xr = x + (size_t)row * 512 + lane * 8;
  float4 a = *(const float4*)xr;
  float4 b = *(const float4*)(xr + 4);
  float v[8] = {a.x, a.y, a.z, a.w, b.x, b.y, b.z, b.w};
  float s = 0.f;
#pragma unroll
  for (int e = 0; e < 8; ++e) s += v[e];
#pragma unroll
  for (int m = 1; m < 64; m <<= 1) s += __shfl_xor(s, m);
  float mean = s * (1.f / 512.f);
  float sq = 0.f;
#pragma unroll
  for (int e = 0; e < 8; ++e) { float d = v[e] - mean; sq += d * d; }
#pragma unroll
  for (int m = 1; m < 64; m <<= 1) sq += __shfl_xor(sq, m);
  float rstd = rsqrtf(sq * (1.f / 512.f) + 1e-6f);
  short8 o;
#pragma unroll
  for (int e = 0; e < 8; ++e) o[e] = f2bf((v[e] - mean) * rstd);
  *(short8*)(out + (size_t)row * 512 + lane * 8) = o;
}

// ---------------- NT GEMM: C[R,NC] = A[R,K] * W[NC,K]^T (+bias)(relu)(+res) ----
// 128x128 tile, 256 thr = 4 waves (2x2), wave tile 64x64 = 4x4 frags 16x16.
template <bool BIAS, bool RELU, bool RES, bool OUTBF>
__global__ __launch_bounds__(256) void gemm_nt(
    const short* __restrict__ A, const short* __restrict__ W,
    const float* __restrict__ bias, const float* __restrict__ res,
    void* __restrict__ outp, int R, int NC, int K) {
  __shared__ short As[128][40];  // +8 pad
  __shared__ short Ws[128][40];
  const int t = threadIdx.x;
  const int brow = blockIdx.y * 128, bcol = blockIdx.x * 128;
  const int wid = t >> 6, lane = t & 63;
  const int lr = lane & 15, lk = lane >> 4;
  const int wrow = (wid >> 1) * 64, wcol = (wid & 1) * 64;
  f32x4 acc[4][4] = {};

  const int srow = t >> 1, scol = (t & 1) * 16;
  const short* Ag = A + (size_t)(brow + srow) * K + scol;
  const short* Wg = W + (size_t)(bcol + srow) * K + scol;

  for (int k0 = 0; k0 < K; k0 += 32) {
    short8 a0 = *(const short8*)(Ag + k0);
    short8 a1 = *(const short8*)(Ag + k0 + 8);
    short8 w0 = *(const short8*)(Wg + k0);
    short8 w1 = *(const short8*)(Wg + k0 + 8);
    __syncthreads();  // WAR vs previous iteration's reads
    *(short8*)&As[srow][scol] = a0;
    *(short8*)&As[srow][scol + 8] = a1;
    *(short8*)&Ws[srow][scol] = w0;
    *(short8*)&Ws[srow][scol + 8] = w1;
    __syncthreads();  // RAW
    short8 af[4], bf[4];
#pragma unroll
    for (int mi = 0; mi < 4; ++mi)
      af[mi] = *(const short8*)&As[wrow + mi * 16 + lr][lk * 8];
#pragma unroll
    for (int ni = 0; ni < 4; ++ni)
      bf[ni] = *(const short8*)&Ws[wcol + ni * 16 + lr][lk * 8];
#pragma unroll
    for (int mi = 0; mi < 4; ++mi)
#pragma unroll
      for (int ni = 0; ni < 4; ++ni)
        acc[mi][ni] = __builtin_amdgcn_mfma_f32_16x16x32_bf16(
            af[mi], bf[ni], acc[mi][ni], 0, 0, 0);
  }

#pragma unroll
  for (int mi = 0; mi < 4; ++mi) {
#pragma unroll
    for (int ni = 0; ni < 4; ++ni) {
      int col = bcol + wcol + ni * 16 + lr;
      int row0 = brow + wrow + mi * 16 + lk * 4;
#pragma unroll
      for (int j = 0; j < 4; ++j) {
        float v = acc[mi][ni][j];
        if (BIAS) v += bias[col];
        if (RELU) v = fmaxf(v, 0.f);
        size_t oi = (size_t)(row0 + j) * NC + col;
        if (RES) v += res[oi];
        if (OUTBF) ((short*)outp)[oi] = f2bf(v);
        else       ((float*)outp)[oi] = v;
      }
    }
  }
}

// ---------------- Flash attention ----------------
// grid: (Nq/64, B*H). 256 thr = 4 waves; wave handles 16 q-rows.
// q rows stride qstride (head at h*64); kv rows stride kvstride.
// out: [B*Nq, 512] bf16, head at h*64.
__global__ __launch_bounds__(256) void flash_attn(
    const short* __restrict__ q, const short* __restrict__ k,
    const short* __restrict__ v, short* __restrict__ out,
    int qstride, int kvstride, int Nq, int Nkv, float scale, int H_) {
  __shared__ short Plds[4][16][72];
  __shared__ short Vt[64][72];  // Vt[d][kvrow]
  const int t = threadIdx.x;
  const int wid = t >> 6, lane = t & 63;
  const int lr = lane & 15, lk = lane >> 4;
  const int bh = blockIdx.y;
  const int b = bh / H_, h = bh % H_;
  const int q0 = blockIdx.x * 64 + wid * 16;

  const short* qbase = q + (size_t)(b * Nq + q0 + lr) * qstride + h * 64 + lk * 8;
  short8 qf0 = *(const short8*)(qbase);
  short8 qf1 = *(const short8*)(qbase + 32);

  f32x4 acc_o[4] = {};
  float m_run[4], l_run[4];
#pragma unroll
  for (int j = 0; j < 4; ++j) { m_run[j] = -1e30f; l_run[j] = 0.f; }

  const int vrow = t >> 2, vdb = (t & 3) * 16;

  for (int kt = 0; kt < Nkv; kt += 64) {
    // stage V^T tile (64 kv rows x 64 dims)
    const short* vsrc = v + (size_t)(b * Nkv + kt + vrow) * kvstride + h * 64 + vdb;
    short8 v0 = *(const short8*)vsrc;
    short8 v1 = *(const short8*)(vsrc + 8);
    __syncthreads();  // WAR: previous PV reads done
#pragma unroll
    for (int e = 0; e < 8; ++e) Vt[vdb + e][vrow] = v0[e];
#pragma unroll
    for (int e = 0; e < 8; ++e) Vt[vdb + 8 + e][vrow] = v1[e];

    // S = scale * Q K^T  (16 rows x 64 kv cols per wave)
    f32x4 s[4] = {};
    const short* kbase = k + (size_t)(b * Nkv + kt + lr) * kvstride + h * 64 + lk * 8;
#pragma unroll
    for (int c = 0; c < 4; ++c) {
      const short* kp = kbase + (size_t)c * 16 * kvstride;
      short8 kf0 = *(const short8*)(kp);
      short8 kf1 = *(const short8*)(kp + 32);
      s[c] = __builtin_amdgcn_mfma_f32_16x16x32_bf16(qf0, kf0, s[c], 0, 0, 0);
      s[c] = __builtin_amdgcn_mfma_f32_16x16x32_bf16(qf1, kf1, s[c], 0, 0, 0);
    }
#pragma unroll
    for (int c = 0; c < 4; ++c)
#pragma unroll
      for (int j = 0; j < 4; ++j) s[c][j] *= scale;

    // online softmax (rows = lk*4+j, cols across 16-lane group x 4 chunks)
    float mloc[4];
#pragma unroll
    for (int j = 0; j < 4; ++j)
      mloc[j] = fmaxf(fmaxf(s[0][j], s[1][j]), fmaxf(s[2][j], s[3][j]));
#pragma unroll
    for (int m = 1; m < 16; m <<= 1)
#pragma unroll
      for (int j = 0; j < 4; ++j) mloc[j] = fmaxf(mloc[j], __shfl_xor(mloc[j], m));

    float alpha[4];
#pragma unroll
    for (int j = 0; j < 4; ++j) {
      float mn = fmaxf(m_run[j], mloc[j]);
      alpha[j] = __expf(m_run[j] - mn);
      m_run[j] = mn;
    }
    float p[4][4];
#pragma unroll
    for (int c = 0; c < 4; ++c)
#pragma unroll
      for (int j = 0; j < 4; ++j) p[c][j] = __expf(s[c][j] - m_run[j]);
    float rsum[4];
#pragma unroll
    for (int j = 0; j < 4; ++j)
      rsum[j] = (p[0][j] + p[1][j]) + (p[2][j] + p[3][j]);
#pragma unroll
    for (int m = 1; m < 16; m <<= 1)
#pragma unroll
      for (int j = 0; j < 4; ++j) rsum[j] += __shfl_xor(rsum[j], m);
#pragma unroll
    for (int j = 0; j < 4; ++j) l_run[j] = l_run[j] * alpha[j] + rsum[j];
#pragma unroll
    for (int f = 0; f < 4; ++f)
#pragma unroll
      for (int j = 0; j < 4; ++j) acc_o[f][j] *= alpha[j];

    // P -> LDS (bf16), re-layout for PV A-operand
#pragma unroll
    for (int c = 0; c < 4; ++c)
#pragma unroll
      for (int j = 0; j < 4; ++j)
        Plds[wid][lk * 4 + j][c * 16 + lr] = f2bf(p[c][j]);
    __syncthreads();  // Vt (cross-wave) + Plds RAW

    // O += P @ V
#pragma unroll
    for (int kk = 0; kk < 2; ++kk) {
      short8 pa = *(const short8*)&Plds[wid][lr][kk * 32 + lk * 8];
#pragma unroll
      for (int f = 0; f < 4; ++f) {
        short8 vb = *(const short8*)&Vt[f * 16 + lr][kk * 32 + lk * 8];
        acc_o[f] = __builtin_amdgcn_mfma_f32_16x16x32_bf16(pa, vb, acc_o[f], 0, 0, 0);
      }
    }
  }

  // write O / l
#pragma unroll
  for (int f = 0; f < 4; ++f)
#pragma unroll
    for (int j = 0; j < 4; ++j) {
      size_t oi = (size_t)(b * Nq + q0 + lk * 4 + j) * 512 + h * 64 + f * 16 + lr;
      out[oi] = f2bf(acc_o[f][j] / l_run[j]);
    }
}

// ---------------------------------------------------------------------------
extern "C" void kernel_launch(void* const* d_in, const int* in_sizes, int n_in,
                              void* d_out, int out_size, void* d_ws, size_t ws_size,
                              hipStream_t stream) {
  (void)in_sizes; (void)n_in; (void)out_size; (void)ws_size;
  const float* cond  = (const float*)d_in[0];
  const float* x_in  = (const float*)d_in[1];
  const float* Wqkv  = (const float*)d_in[2];
  const float* b_qkv = (const float*)d_in[3];
  const float* Wo    = (const float*)d_in[4];
  const float* bo    = (const float*)d_in[5];
  const float* Wcq   = (const float*)d_in[6];
  const float* Wck   = (const float*)d_in[7];
  const float* Wcv   = (const float*)d_in[8];
  const float* Wco   = (const float*)d_in[9];
  const float* bco   = (const float*)d_in[10];
  const float* W1    = (const float*)d_in[11];
  const float* b1    = (const float*)d_in[12];
  const float* W2    = (const float*)d_in[13];
  const float* b2    = (const float*)d_in[14];
  float* out = (float*)d_out;

  const int Bv = 4, Nv = 2048, Mv = 512, Ev = 512, CDv = 256, Hv = 8, MHv = 1024;
  const int RN = Bv * Nv;   // 8192
  const int RM = Bv * Mv;   // 2048

  char* ws = (char*)d_ws;
  size_t off = 0;
  auto alloc = [&](size_t bytes) { void* p = ws + off; off += bytes; return p; };

  short* wqkv_b = (short*)alloc((size_t)3 * Ev * Ev * 2);      // 1.5M
  short* wo_b   = (short*)alloc((size_t)Ev * Ev * 2);
  short* wcq_b  = (short*)alloc((size_t)Ev * Ev * 2);
  short* wck_b  = (short*)alloc((size_t)Ev * CDv * 2);
  short* wcv_b  = (short*)alloc((size_t)Ev * CDv * 2);
  short* wco_b  = (short*)alloc((size_t)Ev * Ev * 2);
  short* w1_b   = (short*)alloc((size_t)MHv * Ev * 2);
  short* w2_b   = (short*)alloc((size_t)Ev * MHv * 2);
  short* cond_b = (short*)alloc((size_t)RM * CDv * 2);
  short* xnb    = (short*)alloc((size_t)RN * Ev * 2);          // shared xn/xn2/xn3
  short* sa_b   = (short*)alloc((size_t)RN * Ev * 2);
  float* x1     = (float*)alloc((size_t)RN * Ev * 4);
  float* x2     = (float*)alloc((size_t)RN * Ev * 4);
  char*  qreg   = (char*)alloc((size_t)RN * 3 * Ev * 2);       // 25.2MB region
  short* qkv_b  = (short*)qreg;
  // aliases inside qreg (disjoint lifetimes with qkv):
  short* cq = (short*)(qreg + 0);
  short* ck = (short*)(qreg + (size_t)RN * Ev * 2);                    // +8MB
  short* cv = (short*)(qreg + (size_t)RN * Ev * 2 + (size_t)RM * Ev * 2);  // +10MB
  short* ca = (short*)(qreg + (size_t)RN * Ev * 2 + (size_t)2 * RM * Ev * 2); // +12MB
  short* hb = (short*)(qreg + 0);  // MLP hidden 16MB, after ca consumed

  auto cast = [&](const float* s, short* d, int n) {
    cast_bf16_kernel<<<n / 2048, 256, 0, stream>>>(s, d, n);
  };
  cast(Wqkv, wqkv_b, 3 * Ev * Ev);
  cast(Wo, wo_b, Ev * Ev);
  cast(Wcq, wcq_b, Ev * Ev);
  cast(Wck, wck_b, Ev * CDv);
  cast(Wcv, wcv_b, Ev * CDv);
  cast(Wco, wco_b, Ev * Ev);
  cast(W1, w1_b, MHv * Ev);
  cast(W2, w2_b, Ev * MHv);
  cast(cond, cond_b, RM * CDv);

  dim3 blk(256);

  // 1) LN(x_in) -> xnb
  ln_kernel<<<RN / 4, blk, 0, stream>>>(x_in, xnb, RN);
  // 2) qkv = xnb @ Wqkv^T + b_qkv  (bf16 out)
  gemm_nt<true, false, false, true><<<dim3(3 * Ev / 128, RN / 128), blk, 0, stream>>>(
      xnb, wqkv_b, b_qkv, nullptr, qkv_b, RN, 3 * Ev, Ev);
  // 3) self-attn
  flash_attn<<<dim3(Nv / 64, Bv * Hv), blk, 0, stream>>>(
      qkv_b, qkv_b + Ev, qkv_b + 2 * Ev, sa_b, 3 * Ev, 3 * Ev, Nv, Nv, 0.125f, Hv);
  // 4) x1 = sa @ Wo^T + bo + x_in  (fp32)
  gemm_nt<true, false, true, false><<<dim3(Ev / 128, RN / 128), blk, 0, stream>>>(
      sa_b, wo_b, bo, x_in, x1, RN, Ev, Ev);
  // 5) LN(x1) -> xnb
  ln_kernel<<<RN / 4, blk, 0, stream>>>(x1, xnb, RN);
  // 6) cq = xnb @ Wcq^T (bf16)
  gemm_nt<false, false, false, true><<<dim3(Ev / 128, RN / 128), blk, 0, stream>>>(
      xnb, wcq_b, nullptr, nullptr, cq, RN, Ev, Ev);
  // 7) ck/cv = cond @ Wck^T / Wcv^T (bf16)
  gemm_nt<false, false, false, true><<<dim3(Ev / 128, RM / 128), blk, 0, stream>>>(
      cond_b, wck_b, nullptr, nullptr, ck, RM, Ev, CDv);
  gemm_nt<false, false, false, true><<<dim3(Ev / 128, RM / 128), blk, 0, stream>>>(
      cond_b, wcv_b, nullptr, nullptr, cv, RM, Ev, CDv);
  // 8) cross-attn
  flash_attn<<<dim3(Nv / 64, Bv * Hv), blk, 0, stream>>>(
      cq, ck, cv, ca, Ev, Ev, Nv, Mv, 0.125f, Hv);
  // 9) x2 = ca @ Wco^T + bco + x1 (fp32)
  gemm_nt<true, false, true, false><<<dim3(Ev / 128, RN / 128), blk, 0, stream>>>(
      ca, wco_b, bco, x1, x2, RN, Ev, Ev);
  // 10) LN(x2) -> xnb
  ln_kernel<<<RN / 4, blk, 0, stream>>>(x2, xnb, RN);
  // 11) h = relu(xnb @ W1^T + b1) (bf16)
  gemm_nt<true, true, false, true><<<dim3(MHv / 128, RN / 128), blk, 0, stream>>>(
      xnb, w1_b, b1, nullptr, hb, RN, MHv, Ev);
  // 12) out = relu(h @ W2^T + b2) + x2 (fp32)
  gemm_nt<true, true, true, false><<<dim3(Ev / 128, RN / 128), blk, 0, stream>>>(
      hb, w2_b, b2, x2, out, RN, Ev, MHv);
}

// Round 2
// 317.214 us; speedup vs baseline: 1.1843x; 1.1843x over previous
//
#include <hip/hip_runtime.h>
#include <cstdint>
#include <cstddef>

// ---------------------------------------------------------------------------
// DiT block: LN -> self-attn -> +res -> LN -> cross-attn -> +res -> LN -> MLP
// B=4 N=2048 M=512 E=512 CD=256 H=8 DH=64 MH=1024
// GEMMs: bf16 MFMA 16x16x32, fp32 accum, global_load_lds(16B) staging (m97).
// Attention: swapped-QK^T flash, V^T produced by the upstream GEMM epilogue,
// K/V^T read direct from global (L2-resident), no barriers in the KV loop.
// ---------------------------------------------------------------------------

typedef short short8 __attribute__((ext_vector_type(8)));
typedef short short4v __attribute__((ext_vector_type(4)));
typedef float f32x4 __attribute__((ext_vector_type(4)));

typedef __attribute__((address_space(1))) const void gconst_t;
typedef __attribute__((address_space(3))) void lds_t;

__device__ __forceinline__ void gl_lds16(const void* g, void* l) {
  __builtin_amdgcn_global_load_lds((gconst_t*)g, (lds_t*)l, 16, 0, 0);
}

__device__ __forceinline__ short f2bf(float f) {
  union { float f; unsigned u; } x; x.f = f;
  unsigned r = x.u + 0x7fffu + ((x.u >> 16) & 1u);  // RNE
  return (short)(r >> 16);
}

// ---------------- fused multi-tensor cast fp32 -> bf16 ----------------
struct CastDesc { const float* src; short* dst; int nblk; };
struct CastArgs { CastDesc d[9]; };

__global__ __launch_bounds__(256) void cast_multi(CastArgs a) {
  int bi = blockIdx.x;
#pragma unroll
  for (int i = 0; i < 9; ++i) {
    if (bi < a.d[i].nblk) {
      int idx = (bi * 256 + threadIdx.x) * 8;
      const float* src = a.d[i].src;
      float4 f0 = *(const float4*)(src + idx);
      float4 f1 = *(const float4*)(src + idx + 4);
      short8 o;
      o[0] = f2bf(f0.x); o[1] = f2bf(f0.y); o[2] = f2bf(f0.z); o[3] = f2bf(f0.w);
      o[4] = f2bf(f1.x); o[5] = f2bf(f1.y); o[6] = f2bf(f1.z); o[7] = f2bf(f1.w);
      *(short8*)(a.d[i].dst + idx) = o;
      return;
    }
    bi -= a.d[i].nblk;
  }
}

// ---------------- LayerNorm over 512 cols, 1 wave/row, bf16 out ----------------
__global__ __launch_bounds__(256) void ln_kernel(
    const float* __restrict__ x, short* __restrict__ out, int nrows) {
  int row = blockIdx.x * 4 + (threadIdx.x >> 6);
  int lane = threadIdx.x & 63;
  if (row >= nrows) return;
  const float* xr = x + (size_t)row * 512 + lane * 8;
  float4 a = *(const float4*)xr;
  float4 b = *(const float4*)(xr + 4);
  float v[8] = {a.x, a.y, a.z, a.w, b.x, b.y, b.z, b.w};
  float s = 0.f;
#pragma unroll
  for (int e = 0; e < 8; ++e) s += v[e];
#pragma unroll
  for (int m = 1; m < 64; m <<= 1) s += __shfl_xor(s, m);
  float mean = s * (1.f / 512.f);
  float sq = 0.f;
#pragma unroll
  for (int e = 0; e < 8; ++e) { float d = v[e] - mean; sq += d * d; }
#pragma unroll
  for (int m = 1; m < 64; m <<= 1) sq += __shfl_xor(sq, m);
  float rstd = rsqrtf(sq * (1.f / 512.f) + 1e-6f);
  short8 o;
#pragma unroll
  for (int e = 0; e < 8; ++e) o[e] = f2bf((v[e] - mean) * rstd);
  *(short8*)(out + (size_t)row * 512 + lane * 8) = o;
}

// ---------------- NT GEMM: C[R,NC] = A[R,K] * W[NC,K]^T (+bias)(relu)(+res) ----
// 128x128 tile, 4 waves (2x2), wave tile 64x64 = 4x4 frags. global_load_lds 16B.
// VT: blocks with bcol >= vcol0 write output TRANSPOSED into vt[row', Nkv] where
//     row' = (batch*H*64 + col-vcol0), i.e. V^T layout for the attention PV step.
template <bool BIAS, bool RELU, bool RES, bool OUTBF, bool VT>
__global__ __launch_bounds__(256) void gemm_nt(
    const short* __restrict__ A, const short* __restrict__ W,
    const float* __restrict__ bias, const float* __restrict__ res,
    void* __restrict__ outp, int R, int NC, int K, int gx,
    short* __restrict__ vt, int vcol0, int vn_log2) {
  __shared__ short As[128 * 32];
  __shared__ short Ws[128 * 32];
  const int nwg = gridDim.x;
  const int b0 = blockIdx.x;
  const int bid = ((nwg & 7) == 0) ? ((b0 & 7) * (nwg >> 3) + (b0 >> 3)) : b0;
  const int bx = bid % gx, by = bid / gx;
  const int brow = by * 128, bcol = bx * 128;
  const int t = threadIdx.x;
  const int wid = t >> 6, lane = t & 63;
  const int lr = lane & 15, lk = lane >> 4;
  const int wrow = (wid >> 1) * 64, wcol = (wid & 1) * 64;
  f32x4 acc[4][4] = {};

  // staging: chunk c (of 8) = 16 rows x 64B; wave handles chunks wid*2, wid*2+1
  const int c0 = wid * 2;
  const int srow = c0 * 16 + (lane >> 2);
  const int scol = (lane & 3) * 8;
  const short* Ag = A + (size_t)(brow + srow) * K + scol;
  const short* Wg = W + (size_t)(bcol + srow) * K + scol;
  short* As0 = As + c0 * 512;
  short* Ws0 = Ws + c0 * 512;

  for (int k0 = 0; k0 < K; k0 += 32) {
    __syncthreads();  // WAR: prior fragment reads done
    gl_lds16(Ag + k0, As0);
    gl_lds16(Ag + (size_t)16 * K + k0, As0 + 512);
    gl_lds16(Wg + k0, Ws0);
    gl_lds16(Wg + (size_t)16 * K + k0, Ws0 + 512);
    __syncthreads();  // RAW: barrier drains vmcnt
    short8 af[4], bf[4];
#pragma unroll
    for (int mi = 0; mi < 4; ++mi)
      af[mi] = *(const short8*)&As[(wrow + mi * 16 + lr) * 32 + lk * 8];
#pragma unroll
    for (int ni = 0; ni < 4; ++ni)
      bf[ni] = *(const short8*)&Ws[(wcol + ni * 16 + lr) * 32 + lk * 8];
#pragma unroll
    for (int mi = 0; mi < 4; ++mi)
#pragma unroll
      for (int ni = 0; ni < 4; ++ni)
        acc[mi][ni] = __builtin_amdgcn_mfma_f32_16x16x32_bf16(
            af[mi], bf[ni], acc[mi][ni], 0, 0, 0);
  }

  if (VT && bcol >= vcol0) {
    // transposed V epilogue: vt[(batch*512 + (col-vcol0))][n]
    const int vn_mask = (1 << vn_log2) - 1;
#pragma unroll
    for (int mi = 0; mi < 4; ++mi) {
#pragma unroll
      for (int ni = 0; ni < 4; ++ni) {
        int col = bcol + wcol + ni * 16 + lr;
        int vc = col - vcol0;
        int r0 = brow + wrow + mi * 16 + lk * 4;
        int bb = r0 >> vn_log2;
        int n = r0 & vn_mask;
        float bv = BIAS ? bias[col] : 0.f;
        short4v o;
#pragma unroll
        for (int j = 0; j < 4; ++j) o[j] = f2bf(acc[mi][ni][j] + bv);
        *(short4v*)(vt + (((size_t)(bb * 512 + vc)) << vn_log2) + n) = o;
      }
    }
    return;
  }

#pragma unroll
  for (int mi = 0; mi < 4; ++mi) {
#pragma unroll
    for (int ni = 0; ni < 4; ++ni) {
      int col = bcol + wcol + ni * 16 + lr;
      int row0 = brow + wrow + mi * 16 + lk * 4;
      float bv = BIAS ? bias[col] : 0.f;
#pragma unroll
      for (int j = 0; j < 4; ++j) {
        float v = acc[mi][ni][j] + bv;
        if (RELU) v = fmaxf(v, 0.f);
        size_t oi = (size_t)(row0 + j) * NC + col;
        if (RES) v += res[oi];
        if (OUTBF) ((short*)outp)[oi] = f2bf(v);
        else       ((float*)outp)[oi] = v;
      }
    }
  }
}

// ---------------- Flash attention v2 (swapped QK^T, V^T from global) ---------
// grid: 1D, (Nq/128)*B*H blocks of 256 thr = 4 waves; wave owns 32 q-rows
// (2 tiles of 16). Per KV tile (64): S^T = mfma(K,Q) -> lane owns one q-row's
// scores (k = c*16+lk*4+j, q = lane&15) -> in-lane softmax + 2 shfl ->
// P via wave-private LDS -> O^T += mfma(V^T, P). No __syncthreads anywhere.
__global__ __launch_bounds__(256) void flash_attn2(
    const short* __restrict__ q, const short* __restrict__ k,
    const short* __restrict__ vt, short* __restrict__ out,
    int qstride, int kstride, int Nq, int Nkv, int vn_log2, float scale, int H_) {
  __shared__ short Plds[4][2][16][68];
  const int t = threadIdx.x;
  const int wid = t >> 6, lane = t & 63;
  const int lr = lane & 15, lk = lane >> 4;
  const int nb = gridDim.x;
  const int b0 = blockIdx.x;
  const int bid = ((nb & 7) == 0) ? ((b0 & 7) * (nb >> 3) + (b0 >> 3)) : b0;
  const int gx = Nq >> 7;
  const int bh = bid / gx, qblk = bid - bh * gx;
  const int b = bh / H_, h = bh - b * H_;
  const int q0 = qblk * 128 + wid * 32;

  short8 qf[2][2];
#pragma unroll
  for (int qt = 0; qt < 2; ++qt) {
    const short* qp = q + ((size_t)b * Nq + q0 + qt * 16 + lr) * qstride + h * 64 + lk * 8;
    qf[qt][0] = *(const short8*)qp;
    qf[qt][1] = *(const short8*)(qp + 32);
  }

  f32x4 ot[2][4] = {};
  float m_run[2] = {-1e30f, -1e30f};
  float l_run[2] = {0.f, 0.f};

  const short* kb = k + ((size_t)b * Nkv + lr) * kstride + h * 64 + lk * 8;
  const short* vb = vt + (((size_t)bh * 64 + lr) << vn_log2) + lk * 8;

  for (int kt = 0; kt < Nkv; kt += 64) {
    f32x4 st[2][4] = {};
    const short* kp = kb + (size_t)kt * kstride;
#pragma unroll
    for (int c = 0; c < 4; ++c) {
      short8 kf0 = *(const short8*)kp;
      short8 kf1 = *(const short8*)(kp + 32);
      kp += (size_t)16 * kstride;
      st[0][c] = __builtin_amdgcn_mfma_f32_16x16x32_bf16(kf0, qf[0][0], st[0][c], 0, 0, 0);
      st[0][c] = __builtin_amdgcn_mfma_f32_16x16x32_bf16(kf1, qf[0][1], st[0][c], 0, 0, 0);
      st[1][c] = __builtin_amdgcn_mfma_f32_16x16x32_bf16(kf0, qf[1][0], st[1][c], 0, 0, 0);
      st[1][c] = __builtin_amdgcn_mfma_f32_16x16x32_bf16(kf1, qf[1][1], st[1][c], 0, 0, 0);
    }

#pragma unroll
    for (int qt = 0; qt < 2; ++qt) {
      float mx = st[qt][0][0];
#pragma unroll
      for (int c = 0; c < 4; ++c)
#pragma unroll
        for (int j = 0; j < 4; ++j) mx = fmaxf(mx, st[qt][c][j]);
      mx = fmaxf(mx, __shfl_xor(mx, 16));
      mx = fmaxf(mx, __shfl_xor(mx, 32));
      float mn = fmaxf(m_run[qt], mx);
      float al = __expf((m_run[qt] - mn) * scale);
      m_run[qt] = mn;
      float rs = 0.f;
#pragma unroll
      for (int c = 0; c < 4; ++c)
#pragma unroll
        for (int j = 0; j < 4; ++j) {
          float pv = __expf((st[qt][c][j] - mn) * scale);
          st[qt][c][j] = pv;
          rs += pv;
        }
      rs += __shfl_xor(rs, 16);
      rs += __shfl_xor(rs, 32);
      l_run[qt] = l_run[qt] * al + rs;
#pragma unroll
      for (int f = 0; f < 4; ++f) ot[qt][f] *= al;
      // P -> LDS (b64 writes, bank-floor pattern)
#pragma unroll
      for (int c = 0; c < 4; ++c) {
        short4v pk;
#pragma unroll
        for (int j = 0; j < 4; ++j) pk[j] = f2bf(st[qt][c][j]);
        *(short4v*)&Plds[wid][qt][lr][c * 16 + lk * 4] = pk;
      }
    }

    // B-fragments of P (two b64 each, 8B-aligned)
    short8 pb[2][2];
#pragma unroll
    for (int qt = 0; qt < 2; ++qt)
#pragma unroll
      for (int kk = 0; kk < 2; ++kk) {
        union { short4v h[2]; short8 s; } u;
        u.h[0] = *(const short4v*)&Plds[wid][qt][lr][kk * 32 + lk * 8];
        u.h[1] = *(const short4v*)&Plds[wid][qt][lr][kk * 32 + lk * 8 + 4];
        pb[qt][kk] = u.s;
      }

#pragma unroll
    for (int f = 0; f < 4; ++f) {
      const short* vp = vb + (((size_t)f * 16) << vn_log2) + kt;
      short8 va0 = *(const short8*)vp;
      short8 va1 = *(const short8*)(vp + 32);
      ot[0][f] = __builtin_amdgcn_mfma_f32_16x16x32_bf16(va0, pb[0][0], ot[0][f], 0, 0, 0);
      ot[0][f] = __builtin_amdgcn_mfma_f32_16x16x32_bf16(va1, pb[0][1], ot[0][f], 0, 0, 0);
      ot[1][f] = __builtin_amdgcn_mfma_f32_16x16x32_bf16(va0, pb[1][0], ot[1][f], 0, 0, 0);
      ot[1][f] = __builtin_amdgcn_mfma_f32_16x16x32_bf16(va1, pb[1][1], ot[1][f], 0, 0, 0);
    }
  }

#pragma unroll
  for (int qt = 0; qt < 2; ++qt) {
    float inv = 1.f / l_run[qt];
    short* orow = out + ((size_t)b * Nq + q0 + qt * 16 + lr) * 512 + h * 64 + lk * 4;
#pragma unroll
    for (int f = 0; f < 4; ++f) {
      short4v o;
#pragma unroll
      for (int j = 0; j < 4; ++j) o[j] = f2bf(ot[qt][f][j] * inv);
      *(short4v*)(orow + f * 16) = o;
    }
  }
}

// ---------------------------------------------------------------------------
extern "C" void kernel_launch(void* const* d_in, const int* in_sizes, int n_in,
                              void* d_out, int out_size, void* d_ws, size_t ws_size,
                              hipStream_t stream) {
  (void)in_sizes; (void)n_in; (void)out_size; (void)ws_size;
  const float* cond  = (const float*)d_in[0];
  const float* x_in  = (const float*)d_in[1];
  const float* Wqkv  = (const float*)d_in[2];
  const float* b_qkv = (const float*)d_in[3];
  const float* Wo    = (const float*)d_in[4];
  const float* bo    = (const float*)d_in[5];
  const float* Wcq   = (const float*)d_in[6];
  const float* Wck   = (const float*)d_in[7];
  const float* Wcv   = (const float*)d_in[8];
  const float* Wco   = (const float*)d_in[9];
  const float* bco   = (const float*)d_in[10];
  const float* W1    = (const float*)d_in[11];
  const float* b1    = (const float*)d_in[12];
  const float* W2    = (const float*)d_in[13];
  const float* b2    = (const float*)d_in[14];
  float* out = (float*)d_out;

  const int Bv = 4, Nv = 2048, Mv = 512, Ev = 512, Hv = 8, MHv = 1024, CDv = 256;
  const int RN = Bv * Nv;   // 8192
  const int RM = Bv * Mv;   // 2048

  char* ws = (char*)d_ws;
  size_t off = 0;
  auto alloc = [&](size_t bytes) { void* p = ws + off; off += bytes; return p; };

  short* wqkv_b = (short*)alloc((size_t)3 * Ev * Ev * 2);
  short* wo_b   = (short*)alloc((size_t)Ev * Ev * 2);
  short* wcq_b  = (short*)alloc((size_t)Ev * Ev * 2);
  short* wck_b  = (short*)alloc((size_t)Ev * CDv * 2);
  short* wcv_b  = (short*)alloc((size_t)Ev * CDv * 2);
  short* wco_b  = (short*)alloc((size_t)Ev * Ev * 2);
  short* w1_b   = (short*)alloc((size_t)MHv * Ev * 2);
  short* w2_b   = (short*)alloc((size_t)Ev * MHv * 2);
  short* cond_b = (short*)alloc((size_t)RM * CDv * 2);
  short* xnb    = (short*)alloc((size_t)RN * Ev * 2);          // xn/xn2/xn3
  short* sa_b   = (short*)alloc((size_t)RN * Ev * 2);
  float* x1     = (float*)alloc((size_t)RN * Ev * 4);
  float* x2     = (float*)alloc((size_t)RN * Ev * 4);
  char*  qreg   = (char*)alloc((size_t)RN * 3 * Ev * 2);       // 25.2MB region
  short* qkv_b  = (short*)qreg;                                 // q,k cols live here
  // aliases (disjoint lifetimes):
  short* cq   = (short*)(qreg + 0);                                       // step 6-8
  short* ck   = (short*)(qreg + (size_t)RN * Ev * 2);                     // step 7-8
  short* vt_c = (short*)(qreg + (size_t)RN * Ev * 2 + (size_t)RM * Ev * 2);  // cv^T
  short* ca   = (short*)(qreg + (size_t)RN * Ev * 2 + (size_t)2 * RM * Ev * 2);
  short* hb   = (short*)(qreg + 0);          // MLP hidden, after cross-attn
  short* vt_s = (short*)x2;                  // self V^T (8.4MB), dead before x2 write

  // fused weight/cond casts (all sizes % 2048 == 0)
  CastArgs ca_args;
  const float* srcs[9] = {Wqkv, Wo, Wcq, Wck, Wcv, Wco, W1, W2, cond};
  short* dsts[9] = {wqkv_b, wo_b, wcq_b, wck_b, wcv_b, wco_b, w1_b, w2_b, cond_b};
  int ns[9] = {3*Ev*Ev, Ev*Ev, Ev*Ev, Ev*CDv, Ev*CDv, Ev*Ev, MHv*Ev, Ev*MHv, RM*CDv};
  int tot_blk = 0;
  for (int i = 0; i < 9; ++i) {
    ca_args.d[i].src = srcs[i]; ca_args.d[i].dst = dsts[i];
    ca_args.d[i].nblk = ns[i] / 2048; tot_blk += ca_args.d[i].nblk;
  }
  cast_multi<<<tot_blk, 256, 0, stream>>>(ca_args);

  dim3 blk(256);

  // 1) LN(x_in) -> xnb
  ln_kernel<<<RN / 4, blk, 0, stream>>>(x_in, xnb, RN);
  // 2) qkv: q,k cols -> qkv_b (stride 1536); v cols -> vt_s transposed
  gemm_nt<true, false, false, true, true><<<(3 * Ev / 128) * (RN / 128), blk, 0, stream>>>(
      xnb, wqkv_b, b_qkv, nullptr, qkv_b, RN, 3 * Ev, Ev, 3 * Ev / 128,
      vt_s, 2 * Ev, 11);
  // 3) self-attn: q=qkv cols 0..511, k=cols 512..1023, v^T=vt_s
  flash_attn2<<<(Nv / 128) * Bv * Hv, blk, 0, stream>>>(
      qkv_b, qkv_b + Ev, vt_s, sa_b, 3 * Ev, 3 * Ev, Nv, Nv, 11, 0.125f, Hv);
  // 4) x1 = sa @ Wo^T + bo + x_in
  gemm_nt<true, false, true, false, false><<<(Ev / 128) * (RN / 128), blk, 0, stream>>>(
      sa_b, wo_b, bo, x_in, x1, RN, Ev, Ev, Ev / 128, nullptr, 0, 0);
  // 5) LN(x1) -> xnb
  ln_kernel<<<RN / 4, blk, 0, stream>>>(x1, xnb, RN);
  // 6) cq = xnb @ Wcq^T
  gemm_nt<false, false, false, true, false><<<(Ev / 128) * (RN / 128), blk, 0, stream>>>(
      xnb, wcq_b, nullptr, nullptr, cq, RN, Ev, Ev, Ev / 128, nullptr, 0, 0);
  // 7) ck = cond @ Wck^T ; cv^T -> vt_c
  gemm_nt<false, false, false, true, false><<<(Ev / 128) * (RM / 128), blk, 0, stream>>>(
      cond_b, wck_b, nullptr, nullptr, ck, RM, Ev, CDv, Ev / 128, nullptr, 0, 0);
  gemm_nt<false, false, false, true, true><<<(Ev / 128) * (RM / 128), blk, 0, stream>>>(
      cond_b, wcv_b, nullptr, nullptr, nullptr, RM, Ev, CDv, Ev / 128,
      vt_c, 0, 9);
  // 8) cross-attn
  flash_attn2<<<(Nv / 128) * Bv * Hv, blk, 0, stream>>>(
      cq, ck, vt_c, ca, Ev, Ev, Nv, Mv, 9, 0.125f, Hv);
  // 9) x2 = ca @ Wco^T + bco + x1
  gemm_nt<true, false, true, false, false><<<(Ev / 128) * (RN / 128), blk, 0, stream>>>(
      ca, wco_b, bco, x1, x2, RN, Ev, Ev, Ev / 128, nullptr, 0, 0);
  // 10) LN(x2) -> xnb
  ln_kernel<<<RN / 4, blk, 0, stream>>>(x2, xnb, RN);
  // 11) h = relu(xnb @ W1^T + b1)
  gemm_nt<true, true, false, true, false><<<(MHv / 128) * (RN / 128), blk, 0, stream>>>(
      xnb, w1_b, b1, nullptr, hb, RN, MHv, Ev, MHv / 128, nullptr, 0, 0);
  // 12) out = relu(h @ W2^T + b2) + x2
  gemm_nt<true, true, true, false, false><<<(Ev / 128) * (RN / 128), blk, 0, stream>>>(
      hb, w2_b, b2, x2, out, RN, Ev, MHv, Ev / 128, nullptr, 0, 0);
}